// Round 18
// baseline (662.131 us; speedup 1.0000x reference)
//
#include <hip/hip_runtime.h>
#include <hip/hip_bf16.h>
#include <stdint.h>

// ---------- types ----------
typedef __attribute__((ext_vector_type(8))) short short8;   // 8 bf16
typedef __attribute__((ext_vector_type(4))) short short4v;  // 4 bf16 (8 B)
typedef __attribute__((ext_vector_type(4))) float f32x4;
typedef __attribute__((ext_vector_type(4))) float fvec4;

__device__ __forceinline__ short f2bf(float f) {
  unsigned u = __builtin_bit_cast(unsigned, f);
  unsigned r = u + 0x7fffu + ((u >> 16) & 1u);
  return (short)(r >> 16);
}

__device__ __forceinline__ void gload_lds16(const void* g, void* l) {
  __builtin_amdgcn_global_load_lds(
      (const __attribute__((address_space(1))) void*)g,
      (__attribute__((address_space(3))) void*)l, 16, 0, 0);
}

// Problem: x[64,64,500,12], adj[500,500], W[64,576], b[64]; out[64,64,500,12]
// M = I + 0.125*adj. K-axis (k,w): 9*512 = 4608 = 72 kt-tiles of 64.
// Tiled operand layout: tile = [128 r][64 c] bf16, 16 KB, XOR pre-swizzled.
// nchunk=16 keeps the Z chunk (113 MB) mostly L3-resident (R10: worth ~140us).
// This round: biggemm 3-buffer ring -> SINGLE barrier per K-step.
// Race-freedom: STAGE(s+2) targets buf (s+2)%3 == (s-1)%3; every wave's
// lgkmcnt(0) for its step-(s-1) reads precedes its arrival at step s's
// barrier, so at barrier-exit that buffer has no pending readers.
// LDS 72KB -> 2 blocks/CU (R12's 1/CU failure avoided).
#define VP   512
#define TILE_SHORTS 8192
#define PANEL_TILES 72
#define NSTEP 65

__device__ __forceinline__ int tswz(int r, int c) {
  return r * 64 + ((((c >> 3) ^ (r & 7)) << 3) | (c & 7));
}

// ---------- kernel 1: M^0 (I), M^1 tiles, fp32 master, bf16 M1^T ----------
__global__ __launch_bounds__(256) void initM_kernel(const float* __restrict__ adj,
    float* __restrict__ Mpow, short* __restrict__ Mt, short* __restrict__ M1T) {
  int idx = blockIdx.x * 256 + threadIdx.x;
  int v = idx >> 9, w = idx & 511;
  float m = 0.f;
  if (v < 500 && w < 500) m = 0.125f * adj[v * 500 + w] + (v == w ? 1.f : 0.f);
  Mpow[idx] = m;
  M1T[(size_t)w * VP + v] = f2bf(m);
  int bx = v >> 7, r = v & 127, c = w & 63;
  int kt0 = (w >> 6), kt1 = 8 + (w >> 6);
  Mt[(size_t)(bx * PANEL_TILES + kt0) * TILE_SHORTS + tswz(r, c)] =
      f2bf((v == w && v < 500) ? 1.f : 0.f);
  Mt[(size_t)(bx * PANEL_TILES + kt1) * TILE_SHORTS + tswz(r, c)] = f2bf(m);
}

// ---------- kernel 1.5: W -> bf16 fragment-layout pack ----------
__global__ __launch_bounds__(256) void wprep_kernel(const float* __restrict__ W,
    short* __restrict__ Wbf) {
  int idx = blockIdx.x * 256 + threadIdx.x;   // 0..36863 (grid 144)
  int e = idx & 7, l4 = (idx >> 3) & 15, h = (idx >> 7) & 3;
  int ks = (idx >> 9) & 1, jm = (idx >> 10) & 3, k = idx >> 12;
  int o = jm * 16 + l4, c = k * 64 + ks * 32 + h * 8 + e;
  Wbf[idx] = f2bf(W[o * 576 + c]);
}

// ---------- kernel 2: P = src * M1 (B-frag = one short8 from M1T) ----------
__global__ __launch_bounds__(256) void powstep_kernel(const float* __restrict__ src,
    const short* __restrict__ M1T, float* __restrict__ dst,
    short* __restrict__ Mt, int kslice) {
  int tid = threadIdx.x, wv = tid >> 6, lane = tid & 63;
  int tile = blockIdx.x * 4 + wv;
  int tv = tile >> 5, tw = tile & 31;
  int row  = tv * 16 + (lane & 15);
  int colw = tw * 16 + (lane & 15);
  int kgrp = (lane >> 4) * 8;
  const short* mcol = M1T + (size_t)colw * VP;
  f32x4 acc = {0.f, 0.f, 0.f, 0.f};
  for (int k0 = 0; k0 < 512; k0 += 32) {
    int kc = k0 + kgrp;
    fvec4 f0 = *(const fvec4*)&src[row * VP + kc];
    fvec4 f1 = *(const fvec4*)&src[row * VP + kc + 4];
    short8 a;
    for (int t = 0; t < 4; ++t) { a[t] = f2bf(f0[t]); a[4 + t] = f2bf(f1[t]); }
    short8 b = *(const short8*)&mcol[kc];
    acc = __builtin_amdgcn_mfma_f32_16x16x32_bf16(a, b, acc, 0, 0, 0);
  }
  for (int r = 0; r < 4; ++r) {
    int i = (lane >> 4) * 4 + r;
    int vv = tv * 16 + i;
    float val = acc[r];
    dst[vv * VP + colw] = val;
    int bx = vv >> 7, rr = vv & 127, c = colw & 63;
    int kt = kslice * 8 + (colw >> 6);
    Mt[(size_t)(bx * PANEL_TILES + kt) * TILE_SHORTS + tswz(rr, c)] = f2bf(val);
  }
}

// ---------- kernel 2.5: x transpose: x[n,c,w,l] f32 -> xb[n,l,w512,c64] bf16 ----
__global__ __launch_bounds__(256) void xpose_kernel(const float* __restrict__ x,
    short* __restrict__ xb) {
  int t = threadIdx.x, wv = t >> 6, lane = t & 63;
  int p  = blockIdx.x & 1;          // c-half
  int w0 = (blockIdx.x >> 1) * 64;  // 0..448
  int n  = blockIdx.y;
  const float* xs = x + (size_t)n * 64 * 6000;
  __shared__ short xl[32 * 770];
  for (int ci = 0; ci < 8; ++ci) {
    int crow = wv * 8 + ci;
    int c = p * 32 + crow;
    for (int i = 0; i < 3; ++i) {
      int wl = (i * 64 + lane) * 4;
      int gwl = w0 * 12 + wl;
      fvec4 v = {0.f, 0.f, 0.f, 0.f};
      if (gwl + 3 < 6000) {
        v = *(const fvec4*)&xs[(size_t)c * 6000 + gwl];
      } else {
        for (int e = 0; e < 4; ++e)
          if (gwl + e < 6000) v[e] = xs[(size_t)c * 6000 + gwl + e];
      }
      for (int e = 0; e < 4; ++e) xl[crow * 770 + wl + e] = f2bf(v[e]);
    }
  }
  __syncthreads();
  for (int i = 0; i < 12; ++i) {
    int ct = i * 256 + t;
    int bl = ct & 3;
    int w_l = (ct >> 2) & 63;
    int l = ct >> 8;
    short8 s;
    for (int j = 0; j < 8; ++j)
      s[j] = xl[(bl * 8 + j) * 770 + w_l * 12 + l];
    size_t dst = ((size_t)(n * 12 + l) * 512 + w0 + w_l) * 64 + (p * 4 + bl) * 8;
    *(short8*)(xb + dst) = s;
  }
}

// ---------- kernel 3: Z build — register GEMM, pre-packed W, j-split ----------
__global__ __launch_bounds__(256) void zbuild_kernel(const short* __restrict__ xb,
    const short* __restrict__ Wbf, short* __restrict__ Zt, int n0) {
  int t = threadIdx.x, wv = t >> 6, lane = t & 63;
  int bxx = blockIdx.x;            // 0..47
  int jh = bxx & 1;                // j-half
  int lh = bxx >> 1;               // 0..23: l = lh>>1, w-half = lh&1
  int l = lh >> 1, wh = lh & 1;
  int nloc = blockIdx.y;
  int n = n0 + nloc;
  const short* xbase = xb + (size_t)(n * 12 + l) * 512 * 64;
  short8 af[4][2];
  for (int q = 0; q < 4; ++q)
    for (int ks = 0; ks < 2; ++ks) {
      int wrow = wh * 256 + wv * 64 + q * 16 + (lane & 15);
      int cblk = ks * 4 + (lane >> 4);
      af[q][ks] = *(const short8*)(xbase + (size_t)wrow * 64 + cblk * 8);
    }
  int lanebase = (lane & 15) * 12 + l;
  int kt_off = wh * 4 + wv;
  const short* wbase = Wbf + (lane >> 4) * 128 + (lane & 15) * 8;
  for (int j = jh * 18; j < jh * 18 + 18; ++j) {
    int k = j >> 2, jm = j & 3;
    const short* wp = wbase + (size_t)((k * 4 + jm) * 2) * 512;  // ks stride 512
    short8 bw0 = *(const short8*)(wp);
    short8 bw1 = *(const short8*)(wp + 512);
    f32x4 acc[4];
    for (int q = 0; q < 4; ++q) {
      acc[q] = (f32x4){0.f, 0.f, 0.f, 0.f};
      acc[q] = __builtin_amdgcn_mfma_f32_16x16x32_bf16(af[q][0], bw0, acc[q], 0, 0, 0);
      acc[q] = __builtin_amdgcn_mfma_f32_16x16x32_bf16(af[q][1], bw1, acc[q], 0, 0, 0);
    }
    int zr = jm * 192 + lanebase;
    int pr = zr >> 7, rr = zr & 127;
    size_t tbase = ((size_t)(nloc * 6 + pr) * PANEL_TILES + k * 8 + kt_off) * TILE_SHORTS
                 + rr * 64;
    for (int q = 0; q < 4; ++q) {
      int c4 = q * 16 + (lane >> 4) * 4;
      size_t idx = tbase + ((((c4 >> 3) ^ (zr & 7)) << 3) | (c4 & 7));
      short4v s;
      for (int e = 0; e < 4; ++e) s[e] = f2bf(acc[q][e]);
      *(short4v*)(Zt + idx) = s;
    }
  }
}

// ---------- kernel 4: big batched GEMM (3-buffer ring, single barrier) ----------
// Block: 128 rowM x 64 v, 4 waves each 32x64. Per stage: A 16KB + B 8KB = 6
// gloads/wave. LDS 72KB -> 2 blocks/CU; counted vmcnt(6); ONE barrier/step.
__global__ __launch_bounds__(256) void biggemm_kernel(const short* __restrict__ Zt,
    const short* __restrict__ Mt, const float* __restrict__ bvec,
    float* __restrict__ out, int n0) {
  int tid = threadIdx.x, wv = tid >> 6, lane = tid & 63;
  int nwg = gridDim.x;
  int b = blockIdx.x;
  int swz = (b & 7) * (nwg >> 3) + (b >> 3);   // nwg = 48*cn, always % 8 == 0
  int bx = swz & 7;                // v-tile of 64, fastest (8 siblings share A)
  int rest = swz >> 3;
  int by = rest % 6;
  int bz = rest / 6;
  int v0    = bx * 64;
  int rowM0 = by * 128;
  int n = n0 + bz;
  __shared__ short As[3][TILE_SHORTS];       // 3 x 16 KiB
  __shared__ short Bs[3][TILE_SHORTS / 2];   // 3 x 8 KiB  (72 KiB total)
  f32x4 acc[2][4];
  for (int i = 0; i < 2; ++i)
    for (int j = 0; j < 4; ++j) acc[i][j] = (f32x4){0.f, 0.f, 0.f, 0.f};
  const char* Apanel = (const char*)(Zt + (size_t)(bz * 6 + by) * PANEL_TILES * TILE_SHORTS);
  const char* Bpanel = (const char*)(Mt + (size_t)(bx >> 1) * PANEL_TILES * TILE_SHORTS)
                     + (bx & 1) * 8192;

  // step -> kt: k=0 B-rows identity; only kt == bx nonzero for this v-range.
  auto ktmap = [&](int s) { return (s == 0) ? bx : (s + 7); };

  auto STAGE = [&](int p, int kt) {
    const char* a  = Apanel + (size_t)kt * (TILE_SHORTS * 2);
    const char* bb = Bpanel + (size_t)kt * (TILE_SHORTS * 2);
#pragma unroll
    for (int cc = 0; cc < 4; ++cc) {
      int chunk = cc * 4 + wv;                 // 0..15
      int off = chunk * 1024 + lane * 16;      // linear 1KB per instruction
      gload_lds16(a + off, (char*)As[p] + chunk * 1024);
    }
#pragma unroll
    for (int cc = 0; cc < 2; ++cc) {
      int chunk = cc * 4 + wv;                 // 0..7
      int off = chunk * 1024 + lane * 16;
      gload_lds16(bb + off, (char*)Bs[p] + chunk * 1024);
    }
  };

  // prologue: two K-steps in flight (12 outstanding gloads/wave)
  STAGE(0, ktmap(0));
  STAGE(1, ktmap(1));

  int d = 0;                                  // s % 3
  for (int s = 0; s < NSTEP; ++s) {
    // wait step s's 6 loads; keep s+1's 6 in flight (never 0 mid-loop)
    if (s < NSTEP - 1) {
      asm volatile("s_waitcnt vmcnt(6)" ::: "memory");
    } else {
      asm volatile("s_waitcnt vmcnt(0)" ::: "memory");
    }
    __builtin_amdgcn_sched_barrier(0);
    __builtin_amdgcn_s_barrier();
    // Single barrier: buf[d] complete (each wave waited its own vmcnt), and
    // buf[(d+2)%3] has no pending readers (their lgkmcnt(0) was pre-barrier).

    // refill the dead buffer; lands ~2 steps from now
    int p2 = (d + 2 >= 3) ? d - 1 : d + 2;
    if (s + 2 < NSTEP) STAGE(p2, ktmap(s + 2));

    short8 af[2][2], bf[2][4];
#pragma unroll
    for (int kk = 0; kk < 2; ++kk) {
      int cbyte = kk * 64 + (lane >> 4) * 16;
#pragma unroll
      for (int mi = 0; mi < 2; ++mi) {
        int r = wv * 32 + mi * 16 + (lane & 15);
        af[kk][mi] = *(const short8*)((const char*)As[d] + r * 128 + (cbyte ^ ((r & 7) << 4)));
      }
#pragma unroll
      for (int ni = 0; ni < 4; ++ni) {
        int r2 = ni * 16 + (lane & 15);
        bf[kk][ni] = *(const short8*)((const char*)Bs[d] + r2 * 128 + (cbyte ^ ((r2 & 7) << 4)));
      }
    }
    asm volatile("s_waitcnt lgkmcnt(0)" ::: "memory");
    __builtin_amdgcn_sched_barrier(0);

    __builtin_amdgcn_s_setprio(1);
#pragma unroll
    for (int kk = 0; kk < 2; ++kk)
#pragma unroll
      for (int mi = 0; mi < 2; ++mi)
#pragma unroll
        for (int ni = 0; ni < 4; ++ni)
          acc[mi][ni] = __builtin_amdgcn_mfma_f32_16x16x32_bf16(af[kk][mi], bf[kk][ni],
                                                                acc[mi][ni], 0, 0, 0);
    __builtin_amdgcn_s_setprio(0);
    d = (d + 1 >= 3) ? 0 : d + 1;
  }

  for (int mi = 0; mi < 2; ++mi) {
    for (int r = 0; r < 4; ++r) {
      int gm = rowM0 + wv * 32 + mi * 16 + (lane >> 4) * 4 + r;   // = o*12+l
      int o = gm / 12, l = gm - o * 12;
      float bo = bvec[o];
      size_t obase = (((size_t)n * 64 + o) * 500) * 12 + l;
      for (int ni = 0; ni < 4; ++ni) {
        int v = v0 + ni * 16 + (lane & 15);
        if (v < 500) out[obase + (size_t)v * 12] = acc[mi][ni][r] + bo;
      }
    }
  }
}

// ---------- host ----------
extern "C" void kernel_launch(void* const* d_in, const int* in_sizes, int n_in,
                              void* d_out, int out_size, void* d_ws, size_t ws_size,
                              hipStream_t stream) {
  const float* x   = (const float*)d_in[0];
  const float* adj = (const float*)d_in[1];
  const float* W   = (const float*)d_in[2];
  const float* bv  = (const float*)d_in[3];
  float* out = (float*)d_out;
  char* ws = (char*)d_ws;

  size_t off = 0;
  float* Mpow0 = (float*)(ws + off); off += (size_t)512 * 512 * 4;
  float* Mpow1 = (float*)(ws + off); off += (size_t)512 * 512 * 4;
  short* M1T   = (short*)(ws + off); off += (size_t)512 * 512 * 2;
  short* Wbf   = (short*)(ws + off); off += (size_t)36864 * 2;       // 72 KiB
  short* Mt    = (short*)(ws + off); off += (size_t)4 * PANEL_TILES * TILE_SHORTS * 2;
  short* xb    = (short*)(ws + off); off += (size_t)64 * 12 * 512 * 64 * 2;  // 50.3 MB
  short* Zt    = (short*)(ws + off);
  size_t per_n = (size_t)6 * PANEL_TILES * TILE_SHORTS * 2;          // 7,077,888 B
  int nchunk = 1;
  if (ws_size > off) {
    size_t a = (ws_size - off) / per_n;
    nchunk = (a >= 16) ? 16 : (a < 1 ? 1 : (int)a);   // 16 -> Z chunk 113 MB
  }

  hipLaunchKernelGGL(initM_kernel, dim3(1024), dim3(256), 0, stream, adj, Mpow0, Mt, M1T);
  hipLaunchKernelGGL(wprep_kernel, dim3(144), dim3(256), 0, stream, W, Wbf);
  const float* src = Mpow0; float* dst = Mpow1;
  for (int k = 2; k <= 8; ++k) {
    hipLaunchKernelGGL(powstep_kernel, dim3(256), dim3(256), 0, stream, src, M1T, dst, Mt, k);
    float* t = dst; dst = (float*)src; src = t;
  }
  hipLaunchKernelGGL(xpose_kernel, dim3(16, 64), dim3(256), 0, stream, x, xb);
  for (int n0 = 0; n0 < 64; n0 += nchunk) {
    int cn = (64 - n0) < nchunk ? (64 - n0) : nchunk;
    hipLaunchKernelGGL(zbuild_kernel, dim3(48, cn), dim3(256), 0, stream, xb, Wbf, Zt, n0);
    hipLaunchKernelGGL(biggemm_kernel, dim3(48 * cn), dim3(256), 0, stream, Zt, Mt, bv, out, n0);
  }
}

// Round 19
// 658.354 us; speedup vs baseline: 1.0057x; 1.0057x over previous
//
#include <hip/hip_runtime.h>
#include <hip/hip_bf16.h>
#include <stdint.h>

// ---------- types ----------
typedef __attribute__((ext_vector_type(8))) short short8;   // 8 bf16
typedef __attribute__((ext_vector_type(4))) short short4v;  // 4 bf16 (8 B)
typedef __attribute__((ext_vector_type(4))) float f32x4;
typedef __attribute__((ext_vector_type(4))) float fvec4;

__device__ __forceinline__ short f2bf(float f) {
  unsigned u = __builtin_bit_cast(unsigned, f);
  unsigned r = u + 0x7fffu + ((u >> 16) & 1u);
  return (short)(r >> 16);
}

__device__ __forceinline__ void gload_lds16(const void* g, void* l) {
  __builtin_amdgcn_global_load_lds(
      (const __attribute__((address_space(1))) void*)g,
      (__attribute__((address_space(3))) void*)l, 16, 0, 0);
}

// Problem: x[64,64,500,12], adj[500,500], W[64,576], b[64]; out[64,64,500,12]
// M = I + 0.125*adj. K-axis (k,w): 9*512 = 4608 = 72 kt-tiles of 64.
// Tiled operand layout: tile = [128 r][64 c] bf16, 16 KB, XOR pre-swizzled.
// Biggemm = R14/R16-proven config (2-buffer, 2-barrier, counted vmcnt(6),
// NSTEP 65). R17 (3-ring single-barrier), R15 (K-split), R12 (depth-3) all
// regressed -> schedule space exhausted; this round tests L3 residency:
// nchunk 16 -> 8 puts the whole Z round-trip (57 MB) + out-chunk + xb-chunk
// (~75 MB total) inside the 256 MB Infinity Cache.
#define VP   512
#define TILE_SHORTS 8192
#define PANEL_TILES 72
#define NSTEP 65

__device__ __forceinline__ int tswz(int r, int c) {
  return r * 64 + ((((c >> 3) ^ (r & 7)) << 3) | (c & 7));
}

// ---------- kernel 1: M^0 (I), M^1 tiles, fp32 master, bf16 M1^T ----------
__global__ __launch_bounds__(256) void initM_kernel(const float* __restrict__ adj,
    float* __restrict__ Mpow, short* __restrict__ Mt, short* __restrict__ M1T) {
  int idx = blockIdx.x * 256 + threadIdx.x;
  int v = idx >> 9, w = idx & 511;
  float m = 0.f;
  if (v < 500 && w < 500) m = 0.125f * adj[v * 500 + w] + (v == w ? 1.f : 0.f);
  Mpow[idx] = m;
  M1T[(size_t)w * VP + v] = f2bf(m);
  int bx = v >> 7, r = v & 127, c = w & 63;
  int kt0 = (w >> 6), kt1 = 8 + (w >> 6);
  Mt[(size_t)(bx * PANEL_TILES + kt0) * TILE_SHORTS + tswz(r, c)] =
      f2bf((v == w && v < 500) ? 1.f : 0.f);
  Mt[(size_t)(bx * PANEL_TILES + kt1) * TILE_SHORTS + tswz(r, c)] = f2bf(m);
}

// ---------- kernel 1.5: W -> bf16 fragment-layout pack ----------
__global__ __launch_bounds__(256) void wprep_kernel(const float* __restrict__ W,
    short* __restrict__ Wbf) {
  int idx = blockIdx.x * 256 + threadIdx.x;   // 0..36863 (grid 144)
  int e = idx & 7, l4 = (idx >> 3) & 15, h = (idx >> 7) & 3;
  int ks = (idx >> 9) & 1, jm = (idx >> 10) & 3, k = idx >> 12;
  int o = jm * 16 + l4, c = k * 64 + ks * 32 + h * 8 + e;
  Wbf[idx] = f2bf(W[o * 576 + c]);
}

// ---------- kernel 2: P = src * M1 (B-frag = one short8 from M1T) ----------
__global__ __launch_bounds__(256) void powstep_kernel(const float* __restrict__ src,
    const short* __restrict__ M1T, float* __restrict__ dst,
    short* __restrict__ Mt, int kslice) {
  int tid = threadIdx.x, wv = tid >> 6, lane = tid & 63;
  int tile = blockIdx.x * 4 + wv;
  int tv = tile >> 5, tw = tile & 31;
  int row  = tv * 16 + (lane & 15);
  int colw = tw * 16 + (lane & 15);
  int kgrp = (lane >> 4) * 8;
  const short* mcol = M1T + (size_t)colw * VP;
  f32x4 acc = {0.f, 0.f, 0.f, 0.f};
  for (int k0 = 0; k0 < 512; k0 += 32) {
    int kc = k0 + kgrp;
    fvec4 f0 = *(const fvec4*)&src[row * VP + kc];
    fvec4 f1 = *(const fvec4*)&src[row * VP + kc + 4];
    short8 a;
    for (int t = 0; t < 4; ++t) { a[t] = f2bf(f0[t]); a[4 + t] = f2bf(f1[t]); }
    short8 b = *(const short8*)&mcol[kc];
    acc = __builtin_amdgcn_mfma_f32_16x16x32_bf16(a, b, acc, 0, 0, 0);
  }
  for (int r = 0; r < 4; ++r) {
    int i = (lane >> 4) * 4 + r;
    int vv = tv * 16 + i;
    float val = acc[r];
    dst[vv * VP + colw] = val;
    int bx = vv >> 7, rr = vv & 127, c = colw & 63;
    int kt = kslice * 8 + (colw >> 6);
    Mt[(size_t)(bx * PANEL_TILES + kt) * TILE_SHORTS + tswz(rr, c)] = f2bf(val);
  }
}

// ---------- kernel 2.5: x transpose: x[n,c,w,l] f32 -> xb[n,l,w512,c64] bf16 ----
__global__ __launch_bounds__(256) void xpose_kernel(const float* __restrict__ x,
    short* __restrict__ xb) {
  int t = threadIdx.x, wv = t >> 6, lane = t & 63;
  int p  = blockIdx.x & 1;          // c-half
  int w0 = (blockIdx.x >> 1) * 64;  // 0..448
  int n  = blockIdx.y;
  const float* xs = x + (size_t)n * 64 * 6000;
  __shared__ short xl[32 * 770];
  for (int ci = 0; ci < 8; ++ci) {
    int crow = wv * 8 + ci;
    int c = p * 32 + crow;
    for (int i = 0; i < 3; ++i) {
      int wl = (i * 64 + lane) * 4;
      int gwl = w0 * 12 + wl;
      fvec4 v = {0.f, 0.f, 0.f, 0.f};
      if (gwl + 3 < 6000) {
        v = *(const fvec4*)&xs[(size_t)c * 6000 + gwl];
      } else {
        for (int e = 0; e < 4; ++e)
          if (gwl + e < 6000) v[e] = xs[(size_t)c * 6000 + gwl + e];
      }
      for (int e = 0; e < 4; ++e) xl[crow * 770 + wl + e] = f2bf(v[e]);
    }
  }
  __syncthreads();
  for (int i = 0; i < 12; ++i) {
    int ct = i * 256 + t;
    int bl = ct & 3;
    int w_l = (ct >> 2) & 63;
    int l = ct >> 8;
    short8 s;
    for (int j = 0; j < 8; ++j)
      s[j] = xl[(bl * 8 + j) * 770 + w_l * 12 + l];
    size_t dst = ((size_t)(n * 12 + l) * 512 + w0 + w_l) * 64 + (p * 4 + bl) * 8;
    *(short8*)(xb + dst) = s;
  }
}

// ---------- kernel 3: Z build — register GEMM, pre-packed W, j-split ----------
__global__ __launch_bounds__(256) void zbuild_kernel(const short* __restrict__ xb,
    const short* __restrict__ Wbf, short* __restrict__ Zt, int n0) {
  int t = threadIdx.x, wv = t >> 6, lane = t & 63;
  int bxx = blockIdx.x;            // 0..47
  int jh = bxx & 1;                // j-half
  int lh = bxx >> 1;               // 0..23: l = lh>>1, w-half = lh&1
  int l = lh >> 1, wh = lh & 1;
  int nloc = blockIdx.y;
  int n = n0 + nloc;
  const short* xbase = xb + (size_t)(n * 12 + l) * 512 * 64;
  short8 af[4][2];
  for (int q = 0; q < 4; ++q)
    for (int ks = 0; ks < 2; ++ks) {
      int wrow = wh * 256 + wv * 64 + q * 16 + (lane & 15);
      int cblk = ks * 4 + (lane >> 4);
      af[q][ks] = *(const short8*)(xbase + (size_t)wrow * 64 + cblk * 8);
    }
  int lanebase = (lane & 15) * 12 + l;
  int kt_off = wh * 4 + wv;
  const short* wbase = Wbf + (lane >> 4) * 128 + (lane & 15) * 8;
  for (int j = jh * 18; j < jh * 18 + 18; ++j) {
    int k = j >> 2, jm = j & 3;
    const short* wp = wbase + (size_t)((k * 4 + jm) * 2) * 512;  // ks stride 512
    short8 bw0 = *(const short8*)(wp);
    short8 bw1 = *(const short8*)(wp + 512);
    f32x4 acc[4];
    for (int q = 0; q < 4; ++q) {
      acc[q] = (f32x4){0.f, 0.f, 0.f, 0.f};
      acc[q] = __builtin_amdgcn_mfma_f32_16x16x32_bf16(af[q][0], bw0, acc[q], 0, 0, 0);
      acc[q] = __builtin_amdgcn_mfma_f32_16x16x32_bf16(af[q][1], bw1, acc[q], 0, 0, 0);
    }
    int zr = jm * 192 + lanebase;
    int pr = zr >> 7, rr = zr & 127;
    size_t tbase = ((size_t)(nloc * 6 + pr) * PANEL_TILES + k * 8 + kt_off) * TILE_SHORTS
                 + rr * 64;
    for (int q = 0; q < 4; ++q) {
      int c4 = q * 16 + (lane >> 4) * 4;
      size_t idx = tbase + ((((c4 >> 3) ^ (zr & 7)) << 3) | (c4 & 7));
      short4v s;
      for (int e = 0; e < 4; ++e) s[e] = f2bf(acc[q][e]);
      *(short4v*)(Zt + idx) = s;
    }
  }
}

// ---------- kernel 4: big batched GEMM (R14/R16-proven config) ----------
// Block: 128 rowM x 64 v, 4 waves each 32x64. Per stage: A 16KB + B 8KB = 6
// gloads/wave. LDS 48KB -> 3 blocks/CU; counted vmcnt(6); 2 barriers/step.
__global__ __launch_bounds__(256) void biggemm_kernel(const short* __restrict__ Zt,
    const short* __restrict__ Mt, const float* __restrict__ bvec,
    float* __restrict__ out, int n0) {
  int tid = threadIdx.x, wv = tid >> 6, lane = tid & 63;
  int nwg = gridDim.x;
  int b = blockIdx.x;
  int swz = (b & 7) * (nwg >> 3) + (b >> 3);   // nwg = 48*cn, always % 8 == 0
  int bx = swz & 7;                // v-tile of 64, fastest (8 siblings share A)
  int rest = swz >> 3;
  int by = rest % 6;
  int bz = rest / 6;
  int v0    = bx * 64;
  int rowM0 = by * 128;
  int n = n0 + bz;
  __shared__ short As[2][TILE_SHORTS];       // 2 x 16 KiB
  __shared__ short Bs[2][TILE_SHORTS / 2];   // 2 x 8 KiB  (48 KiB total)
  f32x4 acc[2][4];
  for (int i = 0; i < 2; ++i)
    for (int j = 0; j < 4; ++j) acc[i][j] = (f32x4){0.f, 0.f, 0.f, 0.f};
  const char* Apanel = (const char*)(Zt + (size_t)(bz * 6 + by) * PANEL_TILES * TILE_SHORTS);
  const char* Bpanel = (const char*)(Mt + (size_t)(bx >> 1) * PANEL_TILES * TILE_SHORTS)
                     + (bx & 1) * 8192;

  // step -> kt: k=0 B-rows identity; only kt == bx nonzero for this v-range.
  auto ktmap = [&](int s) { return (s == 0) ? bx : (s + 7); };

  auto STAGE = [&](int p, int kt) {
    const char* a  = Apanel + (size_t)kt * (TILE_SHORTS * 2);
    const char* bb = Bpanel + (size_t)kt * (TILE_SHORTS * 2);
#pragma unroll
    for (int cc = 0; cc < 4; ++cc) {
      int chunk = cc * 4 + wv;                 // 0..15
      int off = chunk * 1024 + lane * 16;      // linear 1KB per instruction
      gload_lds16(a + off, (char*)As[p] + chunk * 1024);
    }
#pragma unroll
    for (int cc = 0; cc < 2; ++cc) {
      int chunk = cc * 4 + wv;                 // 0..7
      int off = chunk * 1024 + lane * 16;
      gload_lds16(bb + off, (char*)Bs[p] + chunk * 1024);
    }
  };

  // prologue: two K-steps in flight (12 outstanding gloads/wave)
  STAGE(0, ktmap(0));
  STAGE(1, ktmap(1));

  for (int s = 0; s < NSTEP; ++s) {
    int d = s & 1;
    if (s < NSTEP - 1) {
      asm volatile("s_waitcnt vmcnt(6)" ::: "memory");
    } else {
      asm volatile("s_waitcnt vmcnt(0)" ::: "memory");
    }
    __builtin_amdgcn_sched_barrier(0);
    __builtin_amdgcn_s_barrier();          // dbuf[d] visible to all waves

    short8 af[2][2], bf[2][4];
#pragma unroll
    for (int kk = 0; kk < 2; ++kk) {
      int cbyte = kk * 64 + (lane >> 4) * 16;
#pragma unroll
      for (int mi = 0; mi < 2; ++mi) {
        int r = wv * 32 + mi * 16 + (lane & 15);
        af[kk][mi] = *(const short8*)((const char*)As[d] + r * 128 + (cbyte ^ ((r & 7) << 4)));
      }
#pragma unroll
      for (int ni = 0; ni < 4; ++ni) {
        int r2 = ni * 16 + (lane & 15);
        bf[kk][ni] = *(const short8*)((const char*)Bs[d] + r2 * 128 + (cbyte ^ ((r2 & 7) << 4)));
      }
    }
    asm volatile("s_waitcnt lgkmcnt(0)" ::: "memory");   // this wave's reads done
    __builtin_amdgcn_sched_barrier(0);
    __builtin_amdgcn_s_barrier();          // ALL waves' reads done -> dbuf[d] dead

    if (s + 2 < NSTEP) STAGE(d, ktmap(s + 2));

    __builtin_amdgcn_s_setprio(1);
#pragma unroll
    for (int kk = 0; kk < 2; ++kk)
#pragma unroll
      for (int mi = 0; mi < 2; ++mi)
#pragma unroll
        for (int ni = 0; ni < 4; ++ni)
          acc[mi][ni] = __builtin_amdgcn_mfma_f32_16x16x32_bf16(af[kk][mi], bf[kk][ni],
                                                                acc[mi][ni], 0, 0, 0);
    __builtin_amdgcn_s_setprio(0);
  }

  for (int mi = 0; mi < 2; ++mi) {
    for (int r = 0; r < 4; ++r) {
      int gm = rowM0 + wv * 32 + mi * 16 + (lane >> 4) * 4 + r;   // = o*12+l
      int o = gm / 12, l = gm - o * 12;
      float bo = bvec[o];
      size_t obase = (((size_t)n * 64 + o) * 500) * 12 + l;
      for (int ni = 0; ni < 4; ++ni) {
        int v = v0 + ni * 16 + (lane & 15);
        if (v < 500) out[obase + (size_t)v * 12] = acc[mi][ni][r] + bo;
      }
    }
  }
}

// ---------- host ----------
extern "C" void kernel_launch(void* const* d_in, const int* in_sizes, int n_in,
                              void* d_out, int out_size, void* d_ws, size_t ws_size,
                              hipStream_t stream) {
  const float* x   = (const float*)d_in[0];
  const float* adj = (const float*)d_in[1];
  const float* W   = (const float*)d_in[2];
  const float* bv  = (const float*)d_in[3];
  float* out = (float*)d_out;
  char* ws = (char*)d_ws;

  size_t off = 0;
  float* Mpow0 = (float*)(ws + off); off += (size_t)512 * 512 * 4;
  float* Mpow1 = (float*)(ws + off); off += (size_t)512 * 512 * 4;
  short* M1T   = (short*)(ws + off); off += (size_t)512 * 512 * 2;
  short* Wbf   = (short*)(ws + off); off += (size_t)36864 * 2;       // 72 KiB
  short* Mt    = (short*)(ws + off); off += (size_t)4 * PANEL_TILES * TILE_SHORTS * 2;
  short* xb    = (short*)(ws + off); off += (size_t)64 * 12 * 512 * 64 * 2;  // 50.3 MB
  short* Zt    = (short*)(ws + off);
  size_t per_n = (size_t)6 * PANEL_TILES * TILE_SHORTS * 2;          // 7,077,888 B
  int nchunk = 1;
  if (ws_size > off) {
    size_t a = (ws_size - off) / per_n;
    // 8 -> Z chunk 57 MB; Z + out-chunk + xb-chunk ~ 75 MB, fully L3-resident
    nchunk = (a >= 8) ? 8 : (a < 1 ? 1 : (int)a);
  }

  hipLaunchKernelGGL(initM_kernel, dim3(1024), dim3(256), 0, stream, adj, Mpow0, Mt, M1T);
  hipLaunchKernelGGL(wprep_kernel, dim3(144), dim3(256), 0, stream, W, Wbf);
  const float* src = Mpow0; float* dst = Mpow1;
  for (int k = 2; k <= 8; ++k) {
    hipLaunchKernelGGL(powstep_kernel, dim3(256), dim3(256), 0, stream, src, M1T, dst, Mt, k);
    float* t = dst; dst = (float*)src; src = t;
  }
  hipLaunchKernelGGL(xpose_kernel, dim3(16, 64), dim3(256), 0, stream, x, xb);
  for (int n0 = 0; n0 < 64; n0 += nchunk) {
    int cn = (64 - n0) < nchunk ? (64 - n0) : nchunk;
    hipLaunchKernelGGL(zbuild_kernel, dim3(48, cn), dim3(256), 0, stream, xb, Wbf, Zt, n0);
    hipLaunchKernelGGL(biggemm_kernel, dim3(48 * cn), dim3(256), 0, stream, Zt, Mt, bv, out, n0);
  }
}

// Round 20
// 505.914 us; speedup vs baseline: 1.3088x; 1.3013x over previous
//
#include <hip/hip_runtime.h>
#include <hip/hip_bf16.h>
#include <stdint.h>

// ---------- types ----------
typedef __attribute__((ext_vector_type(8))) short short8;   // 8 bf16
typedef __attribute__((ext_vector_type(4))) short short4v;  // 4 bf16 (8 B)
typedef __attribute__((ext_vector_type(4))) float f32x4;
typedef __attribute__((ext_vector_type(4))) float fvec4;

__device__ __forceinline__ short f2bf(float f) {
  unsigned u = __builtin_bit_cast(unsigned, f);
  unsigned r = u + 0x7fffu + ((u >> 16) & 1u);
  return (short)(r >> 16);
}

__device__ __forceinline__ void gload_lds16(const void* g, void* l) {
  __builtin_amdgcn_global_load_lds(
      (const __attribute__((address_space(1))) void*)g,
      (__attribute__((address_space(3))) void*)l, 16, 0, 0);
}

// Problem: x[64,64,500,12], adj[500,500], W[64,576], b[64]; out[64,64,500,12]
// M = I + 0.125*adj. K-axis (k,w): 9*512 = 4608 = 72 kt-tiles of 64.
// Tiled operand layout: tile = [128 r][64 c] bf16, 16 KB, XOR pre-swizzled.
// FINAL config = best-measured (R16 bench, 509 us): biggemm 2-buffer/
// 2-barrier/counted-vmcnt(6)/48KB/3 blocks/CU, v-tile 64, NSTEP 65,
// nchunk=16 (grid 768/dispatch keeps 3-blocks/CU supply; R19's nchunk=8
// halved supply and regressed; R10's nchunk=64 broke Z L3-residency).
// Probed and rejected: depth-3 ring (R12), B-in-regs (R13), K-split (R15),
// n-pairing (R17 neutral), 3-ring single-barrier (R18).
#define VP   512
#define TILE_SHORTS 8192
#define PANEL_TILES 72
#define NSTEP 65

__device__ __forceinline__ int tswz(int r, int c) {
  return r * 64 + ((((c >> 3) ^ (r & 7)) << 3) | (c & 7));
}

// ---------- kernel 1: M^0 (I), M^1 tiles, fp32 master, bf16 M1^T ----------
__global__ __launch_bounds__(256) void initM_kernel(const float* __restrict__ adj,
    float* __restrict__ Mpow, short* __restrict__ Mt, short* __restrict__ M1T) {
  int idx = blockIdx.x * 256 + threadIdx.x;
  int v = idx >> 9, w = idx & 511;
  float m = 0.f;
  if (v < 500 && w < 500) m = 0.125f * adj[v * 500 + w] + (v == w ? 1.f : 0.f);
  Mpow[idx] = m;
  M1T[(size_t)w * VP + v] = f2bf(m);
  int bx = v >> 7, r = v & 127, c = w & 63;
  int kt0 = (w >> 6), kt1 = 8 + (w >> 6);
  Mt[(size_t)(bx * PANEL_TILES + kt0) * TILE_SHORTS + tswz(r, c)] =
      f2bf((v == w && v < 500) ? 1.f : 0.f);
  Mt[(size_t)(bx * PANEL_TILES + kt1) * TILE_SHORTS + tswz(r, c)] = f2bf(m);
}

// ---------- kernel 1.5: W -> bf16 fragment-layout pack ----------
__global__ __launch_bounds__(256) void wprep_kernel(const float* __restrict__ W,
    short* __restrict__ Wbf) {
  int idx = blockIdx.x * 256 + threadIdx.x;   // 0..36863 (grid 144)
  int e = idx & 7, l4 = (idx >> 3) & 15, h = (idx >> 7) & 3;
  int ks = (idx >> 9) & 1, jm = (idx >> 10) & 3, k = idx >> 12;
  int o = jm * 16 + l4, c = k * 64 + ks * 32 + h * 8 + e;
  Wbf[idx] = f2bf(W[o * 576 + c]);
}

// ---------- kernel 2: P = src * M1 (B-frag = one short8 from M1T) ----------
__global__ __launch_bounds__(256) void powstep_kernel(const float* __restrict__ src,
    const short* __restrict__ M1T, float* __restrict__ dst,
    short* __restrict__ Mt, int kslice) {
  int tid = threadIdx.x, wv = tid >> 6, lane = tid & 63;
  int tile = blockIdx.x * 4 + wv;
  int tv = tile >> 5, tw = tile & 31;
  int row  = tv * 16 + (lane & 15);
  int colw = tw * 16 + (lane & 15);
  int kgrp = (lane >> 4) * 8;
  const short* mcol = M1T + (size_t)colw * VP;
  f32x4 acc = {0.f, 0.f, 0.f, 0.f};
  for (int k0 = 0; k0 < 512; k0 += 32) {
    int kc = k0 + kgrp;
    fvec4 f0 = *(const fvec4*)&src[row * VP + kc];
    fvec4 f1 = *(const fvec4*)&src[row * VP + kc + 4];
    short8 a;
    for (int t = 0; t < 4; ++t) { a[t] = f2bf(f0[t]); a[4 + t] = f2bf(f1[t]); }
    short8 b = *(const short8*)&mcol[kc];
    acc = __builtin_amdgcn_mfma_f32_16x16x32_bf16(a, b, acc, 0, 0, 0);
  }
  for (int r = 0; r < 4; ++r) {
    int i = (lane >> 4) * 4 + r;
    int vv = tv * 16 + i;
    float val = acc[r];
    dst[vv * VP + colw] = val;
    int bx = vv >> 7, rr = vv & 127, c = colw & 63;
    int kt = kslice * 8 + (colw >> 6);
    Mt[(size_t)(bx * PANEL_TILES + kt) * TILE_SHORTS + tswz(rr, c)] = f2bf(val);
  }
}

// ---------- kernel 2.5: x transpose: x[n,c,w,l] f32 -> xb[n,l,w512,c64] bf16 ----
__global__ __launch_bounds__(256) void xpose_kernel(const float* __restrict__ x,
    short* __restrict__ xb) {
  int t = threadIdx.x, wv = t >> 6, lane = t & 63;
  int p  = blockIdx.x & 1;          // c-half
  int w0 = (blockIdx.x >> 1) * 64;  // 0..448
  int n  = blockIdx.y;
  const float* xs = x + (size_t)n * 64 * 6000;
  __shared__ short xl[32 * 770];
  for (int ci = 0; ci < 8; ++ci) {
    int crow = wv * 8 + ci;
    int c = p * 32 + crow;
    for (int i = 0; i < 3; ++i) {
      int wl = (i * 64 + lane) * 4;
      int gwl = w0 * 12 + wl;
      fvec4 v = {0.f, 0.f, 0.f, 0.f};
      if (gwl + 3 < 6000) {
        v = *(const fvec4*)&xs[(size_t)c * 6000 + gwl];
      } else {
        for (int e = 0; e < 4; ++e)
          if (gwl + e < 6000) v[e] = xs[(size_t)c * 6000 + gwl + e];
      }
      for (int e = 0; e < 4; ++e) xl[crow * 770 + wl + e] = f2bf(v[e]);
    }
  }
  __syncthreads();
  for (int i = 0; i < 12; ++i) {
    int ct = i * 256 + t;
    int bl = ct & 3;
    int w_l = (ct >> 2) & 63;
    int l = ct >> 8;
    short8 s;
    for (int j = 0; j < 8; ++j)
      s[j] = xl[(bl * 8 + j) * 770 + w_l * 12 + l];
    size_t dst = ((size_t)(n * 12 + l) * 512 + w0 + w_l) * 64 + (p * 4 + bl) * 8;
    *(short8*)(xb + dst) = s;
  }
}

// ---------- kernel 3: Z build — register GEMM, pre-packed W, j-split ----------
__global__ __launch_bounds__(256) void zbuild_kernel(const short* __restrict__ xb,
    const short* __restrict__ Wbf, short* __restrict__ Zt, int n0) {
  int t = threadIdx.x, wv = t >> 6, lane = t & 63;
  int bxx = blockIdx.x;            // 0..47
  int jh = bxx & 1;                // j-half
  int lh = bxx >> 1;               // 0..23: l = lh>>1, w-half = lh&1
  int l = lh >> 1, wh = lh & 1;
  int nloc = blockIdx.y;
  int n = n0 + nloc;
  const short* xbase = xb + (size_t)(n * 12 + l) * 512 * 64;
  short8 af[4][2];
  for (int q = 0; q < 4; ++q)
    for (int ks = 0; ks < 2; ++ks) {
      int wrow = wh * 256 + wv * 64 + q * 16 + (lane & 15);
      int cblk = ks * 4 + (lane >> 4);
      af[q][ks] = *(const short8*)(xbase + (size_t)wrow * 64 + cblk * 8);
    }
  int lanebase = (lane & 15) * 12 + l;
  int kt_off = wh * 4 + wv;
  const short* wbase = Wbf + (lane >> 4) * 128 + (lane & 15) * 8;
  for (int j = jh * 18; j < jh * 18 + 18; ++j) {
    int k = j >> 2, jm = j & 3;
    const short* wp = wbase + (size_t)((k * 4 + jm) * 2) * 512;  // ks stride 512
    short8 bw0 = *(const short8*)(wp);
    short8 bw1 = *(const short8*)(wp + 512);
    f32x4 acc[4];
    for (int q = 0; q < 4; ++q) {
      acc[q] = (f32x4){0.f, 0.f, 0.f, 0.f};
      acc[q] = __builtin_amdgcn_mfma_f32_16x16x32_bf16(af[q][0], bw0, acc[q], 0, 0, 0);
      acc[q] = __builtin_amdgcn_mfma_f32_16x16x32_bf16(af[q][1], bw1, acc[q], 0, 0, 0);
    }
    int zr = jm * 192 + lanebase;
    int pr = zr >> 7, rr = zr & 127;
    size_t tbase = ((size_t)(nloc * 6 + pr) * PANEL_TILES + k * 8 + kt_off) * TILE_SHORTS
                 + rr * 64;
    for (int q = 0; q < 4; ++q) {
      int c4 = q * 16 + (lane >> 4) * 4;
      size_t idx = tbase + ((((c4 >> 3) ^ (zr & 7)) << 3) | (c4 & 7));
      short4v s;
      for (int e = 0; e < 4; ++e) s[e] = f2bf(acc[q][e]);
      *(short4v*)(Zt + idx) = s;
    }
  }
}

// ---------- kernel 4: big batched GEMM (R14/R16-proven config) ----------
// Block: 128 rowM x 64 v, 4 waves each 32x64. Per stage: A 16KB + B 8KB = 6
// gloads/wave. LDS 48KB -> 3 blocks/CU; counted vmcnt(6); 2 barriers/step.
__global__ __launch_bounds__(256) void biggemm_kernel(const short* __restrict__ Zt,
    const short* __restrict__ Mt, const float* __restrict__ bvec,
    float* __restrict__ out, int n0) {
  int tid = threadIdx.x, wv = tid >> 6, lane = tid & 63;
  int nwg = gridDim.x;
  int b = blockIdx.x;
  int swz = (b & 7) * (nwg >> 3) + (b >> 3);   // nwg = 48*cn, always % 8 == 0
  int bx = swz & 7;                // v-tile of 64, fastest (8 siblings share A)
  int rest = swz >> 3;
  int by = rest % 6;
  int bz = rest / 6;
  int v0    = bx * 64;
  int rowM0 = by * 128;
  int n = n0 + bz;
  __shared__ short As[2][TILE_SHORTS];       // 2 x 16 KiB
  __shared__ short Bs[2][TILE_SHORTS / 2];   // 2 x 8 KiB  (48 KiB total)
  f32x4 acc[2][4];
  for (int i = 0; i < 2; ++i)
    for (int j = 0; j < 4; ++j) acc[i][j] = (f32x4){0.f, 0.f, 0.f, 0.f};
  const char* Apanel = (const char*)(Zt + (size_t)(bz * 6 + by) * PANEL_TILES * TILE_SHORTS);
  const char* Bpanel = (const char*)(Mt + (size_t)(bx >> 1) * PANEL_TILES * TILE_SHORTS)
                     + (bx & 1) * 8192;

  // step -> kt: k=0 B-rows identity; only kt == bx nonzero for this v-range.
  auto ktmap = [&](int s) { return (s == 0) ? bx : (s + 7); };

  auto STAGE = [&](int p, int kt) {
    const char* a  = Apanel + (size_t)kt * (TILE_SHORTS * 2);
    const char* bb = Bpanel + (size_t)kt * (TILE_SHORTS * 2);
#pragma unroll
    for (int cc = 0; cc < 4; ++cc) {
      int chunk = cc * 4 + wv;                 // 0..15
      int off = chunk * 1024 + lane * 16;      // linear 1KB per instruction
      gload_lds16(a + off, (char*)As[p] + chunk * 1024);
    }
#pragma unroll
    for (int cc = 0; cc < 2; ++cc) {
      int chunk = cc * 4 + wv;                 // 0..7
      int off = chunk * 1024 + lane * 16;
      gload_lds16(bb + off, (char*)Bs[p] + chunk * 1024);
    }
  };

  // prologue: two K-steps in flight (12 outstanding gloads/wave)
  STAGE(0, ktmap(0));
  STAGE(1, ktmap(1));

  for (int s = 0; s < NSTEP; ++s) {
    int d = s & 1;
    if (s < NSTEP - 1) {
      asm volatile("s_waitcnt vmcnt(6)" ::: "memory");
    } else {
      asm volatile("s_waitcnt vmcnt(0)" ::: "memory");
    }
    __builtin_amdgcn_sched_barrier(0);
    __builtin_amdgcn_s_barrier();          // dbuf[d] visible to all waves

    short8 af[2][2], bf[2][4];
#pragma unroll
    for (int kk = 0; kk < 2; ++kk) {
      int cbyte = kk * 64 + (lane >> 4) * 16;
#pragma unroll
      for (int mi = 0; mi < 2; ++mi) {
        int r = wv * 32 + mi * 16 + (lane & 15);
        af[kk][mi] = *(const short8*)((const char*)As[d] + r * 128 + (cbyte ^ ((r & 7) << 4)));
      }
#pragma unroll
      for (int ni = 0; ni < 4; ++ni) {
        int r2 = ni * 16 + (lane & 15);
        bf[kk][ni] = *(const short8*)((const char*)Bs[d] + r2 * 128 + (cbyte ^ ((r2 & 7) << 4)));
      }
    }
    asm volatile("s_waitcnt lgkmcnt(0)" ::: "memory");   // this wave's reads done
    __builtin_amdgcn_sched_barrier(0);
    __builtin_amdgcn_s_barrier();          // ALL waves' reads done -> dbuf[d] dead

    if (s + 2 < NSTEP) STAGE(d, ktmap(s + 2));

    __builtin_amdgcn_s_setprio(1);
#pragma unroll
    for (int kk = 0; kk < 2; ++kk)
#pragma unroll
      for (int mi = 0; mi < 2; ++mi)
#pragma unroll
        for (int ni = 0; ni < 4; ++ni)
          acc[mi][ni] = __builtin_amdgcn_mfma_f32_16x16x32_bf16(af[kk][mi], bf[kk][ni],
                                                                acc[mi][ni], 0, 0, 0);
    __builtin_amdgcn_s_setprio(0);
  }

  for (int mi = 0; mi < 2; ++mi) {
    for (int r = 0; r < 4; ++r) {
      int gm = rowM0 + wv * 32 + mi * 16 + (lane >> 4) * 4 + r;   // = o*12+l
      int o = gm / 12, l = gm - o * 12;
      float bo = bvec[o];
      size_t obase = (((size_t)n * 64 + o) * 500) * 12 + l;
      for (int ni = 0; ni < 4; ++ni) {
        int v = v0 + ni * 16 + (lane & 15);
        if (v < 500) out[obase + (size_t)v * 12] = acc[mi][ni][r] + bo;
      }
    }
  }
}

// ---------- host ----------
extern "C" void kernel_launch(void* const* d_in, const int* in_sizes, int n_in,
                              void* d_out, int out_size, void* d_ws, size_t ws_size,
                              hipStream_t stream) {
  const float* x   = (const float*)d_in[0];
  const float* adj = (const float*)d_in[1];
  const float* W   = (const float*)d_in[2];
  const float* bv  = (const float*)d_in[3];
  float* out = (float*)d_out;
  char* ws = (char*)d_ws;

  size_t off = 0;
  float* Mpow0 = (float*)(ws + off); off += (size_t)512 * 512 * 4;
  float* Mpow1 = (float*)(ws + off); off += (size_t)512 * 512 * 4;
  short* M1T   = (short*)(ws + off); off += (size_t)512 * 512 * 2;
  short* Wbf   = (short*)(ws + off); off += (size_t)36864 * 2;       // 72 KiB
  short* Mt    = (short*)(ws + off); off += (size_t)4 * PANEL_TILES * TILE_SHORTS * 2;
  short* xb    = (short*)(ws + off); off += (size_t)64 * 12 * 512 * 64 * 2;  // 50.3 MB
  short* Zt    = (short*)(ws + off);
  size_t per_n = (size_t)6 * PANEL_TILES * TILE_SHORTS * 2;          // 7,077,888 B
  int nchunk = 1;
  if (ws_size > off) {
    size_t a = (ws_size - off) / per_n;
    nchunk = (a >= 16) ? 16 : (a < 1 ? 1 : (int)a);   // 16 -> grid 768 = 3/CU supply
  }

  hipLaunchKernelGGL(initM_kernel, dim3(1024), dim3(256), 0, stream, adj, Mpow0, Mt, M1T);
  hipLaunchKernelGGL(wprep_kernel, dim3(144), dim3(256), 0, stream, W, Wbf);
  const float* src = Mpow0; float* dst = Mpow1;
  for (int k = 2; k <= 8; ++k) {
    hipLaunchKernelGGL(powstep_kernel, dim3(256), dim3(256), 0, stream, src, M1T, dst, Mt, k);
    float* t = dst; dst = (float*)src; src = t;
  }
  hipLaunchKernelGGL(xpose_kernel, dim3(16, 64), dim3(256), 0, stream, x, xb);
  for (int n0 = 0; n0 < 64; n0 += nchunk) {
    int cn = (64 - n0) < nchunk ? (64 - n0) : nchunk;
    hipLaunchKernelGGL(zbuild_kernel, dim3(48, cn), dim3(256), 0, stream, xb, Wbf, Zt, n0);
    hipLaunchKernelGGL(biggemm_kernel, dim3(48 * cn), dim3(256), 0, stream, Zt, Mt, bv, out, n0);
  }
}